// Round 1
// baseline (2594.276 us; speedup 1.0000x reference)
//
#include <hip/hip_runtime.h>

typedef _Float16 half8 __attribute__((ext_vector_type(8)));
typedef _Float16 half4v __attribute__((ext_vector_type(4)));
typedef float f32x4 __attribute__((ext_vector_type(4)));

#define MFMA_F16 __builtin_amdgcn_mfma_f32_16x16x32_f16

static constexpr int BATCH  = 4096;
static constexpr int DIM    = 512;
static constexpr int CODES  = 16384;
static constexpr int NCB    = 8;
static constexpr int NCHUNK = 8;
static constexpr int CHUNK  = CODES / NCHUNK;   // 2048
static constexpr int NT     = CHUNK / 16;       // 128 tiles of 16 codes
static constexpr int BM     = 64;               // rows per block (4 waves x 16)
static constexpr float LO_SCALE = 2048.0f;
static constexpr float LO_INV   = 1.0f / 2048.0f;

// ---------------- init: residual = z, plus f16 hi/lo split ----------------
__global__ __launch_bounds__(256) void k_init(const float* __restrict__ z,
                                              float* __restrict__ resid,
                                              _Float16* __restrict__ rhi,
                                              _Float16* __restrict__ rlo) {
  int i = blockIdx.x * 256 + threadIdx.x;      // float4 index, 524288 total
  float4 v = ((const float4*)z)[i];
  ((float4*)resid)[i] = v;
  half4v h, l;
  const float* vf = (const float*)&v;
#pragma unroll
  for (int j = 0; j < 4; ++j) {
    float x = vf[j];
    _Float16 hi = (_Float16)x;
    h[j] = hi;
    l[j] = (_Float16)((x - (float)hi) * LO_SCALE);
  }
  *(half4v*)&rhi[(size_t)i * 4] = h;
  *(half4v*)&rlo[(size_t)i * 4] = l;
}

// ---------------- codebook squared norms (f64 accumulate) ----------------
__global__ __launch_bounds__(256) void k_cnorm(const float* __restrict__ cb,
                                               float* __restrict__ cnorm) {
  int wave = threadIdx.x >> 6, lane = threadIdx.x & 63;
  int code = blockIdx.x * 4 + wave;            // 131072 codes total
  const float4* src = (const float4*)(cb + (size_t)code * DIM);
  double s = 0.0;
#pragma unroll
  for (int j = 0; j < 2; ++j) {
    float4 v = src[lane * 2 + j];
    s += (double)v.x * v.x + (double)v.y * v.y + (double)v.z * v.z + (double)v.w * v.w;
  }
#pragma unroll
  for (int off = 32; off; off >>= 1) s += __shfl_down(s, off);
  if (lane == 0) cnorm[code] = (float)s;
}

// ---------------- staging helpers for k_argmin ----------------
__device__ __forceinline__ void load8(const float* __restrict__ cb, int cbase, int nt,
                                      int s_code, int s_kseg, float4 v[8]) {
  const float4* src = (const float4*)(cb + (size_t)(cbase + nt * 16 + s_code) * DIM + s_kseg);
#pragma unroll
  for (int j = 0; j < 8; ++j) v[j] = src[j];
}

__device__ __forceinline__ void cvt_store(_Float16* __restrict__ BHbuf,
                                          _Float16* __restrict__ BLbuf,
                                          int code, int kseg, const float4 sv[8]) {
  const float* f = (const float*)sv;
#pragma unroll
  for (int j = 0; j < 4; ++j) {
    half8 h, l;
#pragma unroll
    for (int e = 0; e < 8; ++e) {
      float x = f[j * 8 + e];
      _Float16 hi = (_Float16)x;
      h[e] = hi;
      l[e] = (_Float16)((x - (float)hi) * LO_SCALE);
    }
    int kk = kseg + j * 8;
    int hw = code * DIM + (kk ^ ((code & 7) << 3));   // 16B-block XOR swizzle
    *(half8*)(BHbuf + hw) = h;
    *(half8*)(BLbuf + hw) = l;
  }
}

// ---------------- per-step argmin over one chunk of 2048 codes ----------------
__global__ __launch_bounds__(256, 2) void k_argmin(
    const _Float16* __restrict__ rhi, const _Float16* __restrict__ rlo,
    const float* __restrict__ cb,      // codebook k base
    const float* __restrict__ cnorm,   // codebook k norms
    float* __restrict__ partmin, int* __restrict__ partidx) {
  __shared__ _Float16 BH[2][16 * DIM];
  __shared__ _Float16 BL[2][16 * DIM];
  __shared__ float CN[CHUNK];

  const int tid   = threadIdx.x;
  const int lane  = tid & 63;
  const int wave  = tid >> 6;
  const int mtile = blockIdx.x >> 3;
  const int chunk = blockIdx.x & 7;    // XCD-pinned chunk
  const int cbase = chunk * CHUNK;

  // stage cnorm chunk to LDS
  {
    const float4* s = (const float4*)(cnorm + cbase);
    float4* d = (float4*)CN;
    for (int i = tid; i < CHUNK / 4; i += 256) d[i] = s[i];
  }

  // A fragments in registers: wave owns 16 rows; lane: row=lane&15, k=(lane>>4)*8
  const int arow = mtile * BM + wave * 16 + (lane & 15);
  const int kb = (lane >> 4) * 8;
  half8 ah[16], al[16];
#pragma unroll
  for (int t = 0; t < 16; ++t) {
    ah[t] = *(const half8*)(rhi + (size_t)arow * DIM + t * 32 + kb);
    al[t] = *(const half8*)(rlo + (size_t)arow * DIM + t * 32 + kb);
  }

  const int s_code = tid >> 4;          // staging map: coalesced global reads
  const int s_kseg = (tid & 15) * 32;

  float rmin[4] = {3.4e38f, 3.4e38f, 3.4e38f, 3.4e38f};
  int   ridx[4] = {0, 0, 0, 0};

  // prologue: stage tile 0 into buffer 0
  {
    float4 v0[8];
    load8(cb, cbase, 0, s_code, s_kseg, v0);
    cvt_store(&BH[0][0], &BL[0][0], s_code, s_kseg, v0);
  }

  const int rcode = lane & 15;          // this lane's output column
  for (int nt = 0; nt < NT; ++nt) {
    __syncthreads();                    // buf[nt&1] staged & visible
    const int cur = nt & 1;
    const bool more = (nt + 1 < NT);
    float4 nv[8];
    if (more) load8(cb, cbase, nt + 1, s_code, s_kseg, nv);   // issue early

    f32x4 acch  = {0.f, 0.f, 0.f, 0.f};
    f32x4 accl0 = {0.f, 0.f, 0.f, 0.f};
    f32x4 accl1 = {0.f, 0.f, 0.f, 0.f};
    const _Float16* bh = &BH[cur][0];
    const _Float16* bl = &BL[cur][0];
#pragma unroll
    for (int t = 0; t < 16; ++t) {
      int kk = t * 32 + kb;
      int hw = rcode * DIM + (kk ^ ((rcode & 7) << 3));
      half8 fbh = *(const half8*)(bh + hw);
      half8 fbl = *(const half8*)(bl + hw);
      acch  = MFMA_F16(ah[t], fbh, acch, 0, 0, 0);
      accl0 = MFMA_F16(ah[t], fbl, accl0, 0, 0, 0);
      accl1 = MFMA_F16(al[t], fbh, accl1, 0, 0, 0);
    }
    float cn = CN[nt * 16 + rcode];
    int codeg = cbase + nt * 16 + rcode;
#pragma unroll
    for (int r = 0; r < 4; ++r) {
      float d = cn - 2.0f * (acch[r] + (accl0[r] + accl1[r]) * LO_INV);
      if (d < rmin[r]) { rmin[r] = d; ridx[r] = codeg; }   // ascending -> first-min
    }
    if (more) cvt_store(&BH[cur ^ 1][0], &BL[cur ^ 1][0], s_code, s_kseg, nv);
  }

  // butterfly min across the 16-lane column group (tie -> smaller index)
#pragma unroll
  for (int s = 1; s < 16; s <<= 1) {
#pragma unroll
    for (int r = 0; r < 4; ++r) {
      float ov = __shfl_xor(rmin[r], s);
      int   oi = __shfl_xor(ridx[r], s);
      if (ov < rmin[r] || (ov == rmin[r] && oi < ridx[r])) { rmin[r] = ov; ridx[r] = oi; }
    }
  }
  if ((lane & 15) == 0) {
    int rowbase = mtile * BM + wave * 16 + (lane >> 4) * 4;
#pragma unroll
    for (int r = 0; r < 4; ++r) {
      partmin[(size_t)(rowbase + r) * NCHUNK + chunk] = rmin[r];
      partidx[(size_t)(rowbase + r) * NCHUNK + chunk] = ridx[r];
    }
  }
}

// ---------------- reduce chunks, gather, update residual/quantized/loss ----------------
__global__ __launch_bounds__(256) void k_update(
    const float* __restrict__ cb, const float* __restrict__ z,
    const float* __restrict__ partmin, const int* __restrict__ partidx,
    float* __restrict__ resid, _Float16* __restrict__ rhi, _Float16* __restrict__ rlo,
    float* __restrict__ quant, float* __restrict__ out_idx,
    float* __restrict__ losspart, int step) {
  __shared__ int s_idx[16];
  __shared__ float s_red[4];
  const int tid = threadIdx.x;
  const int row0 = blockIdx.x * 16;

  if (tid < 16) {
    const int row = row0 + tid;
    float bv = partmin[(size_t)row * NCHUNK];
    int   bi = partidx[(size_t)row * NCHUNK];
#pragma unroll
    for (int c = 1; c < NCHUNK; ++c) {
      float v = partmin[(size_t)row * NCHUNK + c];
      int   i = partidx[(size_t)row * NCHUNK + c];
      if (v < bv || (v == bv && i < bi)) { bv = v; bi = i; }
    }
    s_idx[tid] = bi;
    out_idx[(size_t)row * NCB + step] = (float)bi;
  }
  __syncthreads();

  float lsum = 0.f;
  const int sub = tid >> 7;     // 0/1: which row of the pair
  const int e   = tid & 127;    // float4 index within row
  for (int rp = 0; rp < 16; rp += 2) {
    const int rl = rp + sub;
    const int row = row0 + rl;
    const int idx = s_idx[rl];
    float4 q  = ((const float4*)cb)[(size_t)idx * 128 + e];
    float4 zv = ((const float4*)z)[(size_t)row * 128 + e];
    float4 rv = ((const float4*)resid)[(size_t)row * 128 + e];
    float4 nr, qa;
    const float* qf = (const float*)&q;
    const float* zf = (const float*)&zv;
    const float* rf = (const float*)&rv;
    float* nf = (float*)&nr;
    float* af = (float*)&qa;
    if (step == 0) {
#pragma unroll
      for (int j = 0; j < 4; ++j) af[j] = qf[j];
    } else {
      float4 old = ((const float4*)quant)[(size_t)row * 128 + e];
      const float* of = (const float*)&old;
#pragma unroll
      for (int j = 0; j < 4; ++j) af[j] = of[j] + qf[j];
    }
    ((float4*)quant)[(size_t)row * 128 + e] = qa;
    half4v h, l;
#pragma unroll
    for (int j = 0; j < 4; ++j) {
      float nrj = rf[j] - qf[j];
      nf[j] = nrj;
      _Float16 hi = (_Float16)nrj;
      h[j] = hi;
      l[j] = (_Float16)((nrj - (float)hi) * LO_SCALE);
      float dq = qf[j] - zf[j];
      lsum += dq * dq;
    }
    ((float4*)resid)[(size_t)row * 128 + e] = nr;
    *(half4v*)&rhi[(size_t)row * DIM + e * 4] = h;
    *(half4v*)&rlo[(size_t)row * DIM + e * 4] = l;
  }
#pragma unroll
  for (int off = 32; off; off >>= 1) lsum += __shfl_down(lsum, off);
  if ((tid & 63) == 0) s_red[tid >> 6] = lsum;
  __syncthreads();
  if (tid == 0) losspart[blockIdx.x] = s_red[0] + s_red[1] + s_red[2] + s_red[3];
}

// ---------------- final loss ----------------
__global__ void k_loss(const float* __restrict__ losspart, float* __restrict__ out_loss) {
  if (threadIdx.x == 0 && blockIdx.x == 0) {
    double t = 0.0;
    for (int i = 0; i < NCB * 256; ++i) t += (double)losspart[i];
    out_loss[0] = (float)(t * (1.25 / (double)((size_t)BATCH * DIM)));
  }
}

extern "C" void kernel_launch(void* const* d_in, const int* in_sizes, int n_in,
                              void* d_out, int out_size, void* d_ws, size_t ws_size,
                              hipStream_t stream) {
  const float* z  = (const float*)d_in[0];
  const float* cb = (const float*)d_in[1];
  float* out = (float*)d_out;
  float* quant    = out;                       // [4096*512]
  float* out_loss = out + (size_t)BATCH * DIM; // [1]
  float* out_idx  = out + (size_t)BATCH * DIM + 1; // [4096*8] written as float

  char* ws = (char*)d_ws;
  float*    resid    = (float*)ws;                                  // 8 MB
  _Float16* rhi      = (_Float16*)(ws + ((size_t)8  << 20));        // 4 MB
  _Float16* rlo      = (_Float16*)(ws + ((size_t)12 << 20));        // 4 MB
  float*    cnorm    = (float*)(ws + ((size_t)16 << 20));           // 512 KB
  float*    partmin  = (float*)(ws + ((size_t)16 << 20) + (512 << 10)); // 128 KB
  int*      partidx  = (int*)  (ws + ((size_t)16 << 20) + (640 << 10)); // 128 KB
  float*    losspart = (float*)(ws + ((size_t)16 << 20) + (768 << 10)); // 8 KB

  k_init<<<dim3((BATCH * DIM / 4) / 256), dim3(256), 0, stream>>>(z, resid, rhi, rlo);
  k_cnorm<<<dim3(NCB * CODES / 4), dim3(256), 0, stream>>>(cb, cnorm);

  for (int k = 0; k < NCB; ++k) {
    const float* cbk = cb + (size_t)k * CODES * DIM;
    k_argmin<<<dim3((BATCH / BM) * NCHUNK), dim3(256), 0, stream>>>(
        rhi, rlo, cbk, cnorm + (size_t)k * CODES, partmin, partidx);
    k_update<<<dim3(BATCH / 16), dim3(256), 0, stream>>>(
        cbk, z, partmin, partidx, resid, rhi, rlo,
        quant, out_idx, losspart + k * 256, k);
  }
  k_loss<<<dim3(1), dim3(64), 0, stream>>>(losspart, out_loss);
}